// Round 2
// baseline (252.589 us; speedup 1.0000x reference)
//
#include <hip/hip_runtime.h>
#include <stdint.h>

#define T 4096
#define E 64
#define NWIN 32
#define NBH 32
#define KK_LD 136            // 128 + 8 pad (bf16 elems)
#define VT_LD 136            // 128 + 8 pad (bf16 elems), chunk of 128 keypos
#define PB_STRIDE (16*136)   // per-wave P chunk buffer elems
#define VT_BYTES (64*136*2)      // 17408
#define SMEM_BYTES (256*136*2)   // 69632  -> 2 blocks/CU (139 KB of 160 KB)

typedef __attribute__((ext_vector_type(8))) short short8;
typedef __attribute__((ext_vector_type(4))) short short4v;
typedef __attribute__((ext_vector_type(4))) float f32x4;

__device__ __forceinline__ short f2bf(float x) {
  unsigned u = __float_as_uint(x);
  u += 0x7fffu + ((u >> 16) & 1u);   // round-to-nearest-even
  return (short)(u >> 16);
}

// One block per (window, bh). 8 waves, each owns 16 q-rows.
// LDS plan: phase A = KK [256][136] (K|Kr bf16). phase B overlays it:
//   Vt chunk [64][136] at offset 0, per-wave P chunk [16][136] at +17408.
__global__ __launch_bounds__(512, 4)
void la_kernel(const float* __restrict__ qg, const float* __restrict__ kg,
               const float* __restrict__ qrg, const float* __restrict__ krg,
               const float* __restrict__ vg, float* __restrict__ outg) {
  extern __shared__ char smem[];
  short* KK = (short*)smem;                 // [256][136]
  short* Vt = (short*)smem;                 // chunk phase: [64][136]
  short* Pb = (short*)(smem + VT_BYTES);    // chunk phase: [8][16][136]

  const int w   = blockIdx.x;
  const int bh  = blockIdx.y;
  const int tid = threadIdx.x;
  const int wid  = tid >> 6;    // wave 0..7
  const int lane = tid & 63;
  const int li = lane & 15;
  const int lg = lane >> 4;

  const size_t base = (size_t)bh * T * E;
  const int krow0 = w * 128 - 128;   // global t-row of key-tile row 0

  // ---- Q/Qr -> A-fragments in registers (scale 0.125 folded; exact pow2) ----
  const int qrow = w * 128 + wid * 16 + li;
  const float* qp  = qg  + base + (size_t)qrow * E;
  const float* qrp = qrg + base + (size_t)qrow * E;
  short8 aF[4];
#pragma unroll
  for (int kt = 0; kt < 4; ++kt) {
    const float* sp = (kt < 2 ? qp : qrp) + (kt & 1) * 32 + lg * 8;
    float4 f0 = *(const float4*)sp;
    float4 f1 = *(const float4*)(sp + 4);
    short8 a;
    a[0]=f2bf(f0.x*0.125f); a[1]=f2bf(f0.y*0.125f); a[2]=f2bf(f0.z*0.125f); a[3]=f2bf(f0.w*0.125f);
    a[4]=f2bf(f1.x*0.125f); a[5]=f2bf(f1.y*0.125f); a[6]=f2bf(f1.z*0.125f); a[7]=f2bf(f1.w*0.125f);
    aF[kt] = a;
  }

  // ---- stage K,Kr -> KK[row][0:64 | 64:128], zero-fill for w==0 rows ----
#pragma unroll
  for (int m = 0; m < 2; ++m) {
    const float* src = m ? krg : kg;
#pragma unroll
    for (int it = 0; it < 8; ++it) {
      int idx = it * 512 + tid;
      int row = idx >> 4, c4 = idx & 15;
      int grow = krow0 + row;
      float4 f = make_float4(0.f, 0.f, 0.f, 0.f);
      if (grow >= 0) f = *(const float4*)(src + base + (size_t)grow * E + c4 * 4);
      short4v h = { f2bf(f.x), f2bf(f.y), f2bf(f.z), f2bf(f.w) };
      *(short4v*)(KK + row * KK_LD + m * 64 + c4 * 4) = h;
    }
  }
  __syncthreads();

  // ---- S = [Q|Qr]·[K|Kr]^T : 16 col-tiles x 4 k-tiles of 16x16x32 MFMA ----
  // C-layout: lane holds S[row = lg*4 + reg][col = ct*16 + li]
  f32x4 S[16];
#pragma unroll
  for (int ct = 0; ct < 16; ++ct) {
    f32x4 acc = {0.f, 0.f, 0.f, 0.f};
    const short* kb = KK + (ct * 16 + li) * KK_LD + lg * 8;
#pragma unroll
    for (int kt = 0; kt < 4; ++kt) {
      short8 b = *(const short8*)(kb + kt * 32);
      acc = __builtin_amdgcn_mfma_f32_16x16x32_bf16(aF[kt], b, acc, 0, 0, 0);
    }
    S[ct] = acc;
  }

  // ---- mask + softmax (registers + 16-lane shfl reductions) ----
  const int rowb = wid * 16 + lg * 4;
  float linv[4];
#pragma unroll
  for (int r = 0; r < 4; ++r) {
    const int qi = rowb + r;   // 0..127 within window
    float mx = -1e30f;
#pragma unroll
    for (int ct = 0; ct < 16; ++ct) {
      int jj = ct * 16 + li;   // key col 0..255
      bool valid = (jj <= qi + 128) && (w > 0 || jj >= 128);
      float sv = valid ? S[ct][r] : -1e30f;
      S[ct][r] = sv;
      mx = fmaxf(mx, sv);
    }
    mx = fmaxf(mx, __shfl_xor(mx, 1));
    mx = fmaxf(mx, __shfl_xor(mx, 2));
    mx = fmaxf(mx, __shfl_xor(mx, 4));
    mx = fmaxf(mx, __shfl_xor(mx, 8));
    float sm = 0.f;
#pragma unroll
    for (int ct = 0; ct < 16; ++ct) {
      float e = __expf(S[ct][r] - mx);
      S[ct][r] = e;
      sm += e;
    }
    sm += __shfl_xor(sm, 1);
    sm += __shfl_xor(sm, 2);
    sm += __shfl_xor(sm, 4);
    sm += __shfl_xor(sm, 8);
    linv[r] = 1.f / sm;
  }
  __syncthreads();   // all waves done reading KK; chunk buffers may overlay it

  // ---- O = P·V in two 128-key chunks (LDS overlay of KK region) ----
  f32x4 O[4] = {{0,0,0,0},{0,0,0,0},{0,0,0,0},{0,0,0,0}};
#pragma unroll 1
  for (int c = 0; c < 2; ++c) {
    const bool active = (w > 0) || (c == 1);   // block-uniform
    if (active) {
      // stage V chunk transposed: Vt[e][keypos], e = lane (64 distinct e/wave)
      // b64 writes, stride 68 dwords -> <=2-way per 16-lane phase (free)
      const int rb2 = wid * 16;
      const float* vp = vg + base + (size_t)(krow0 + c * 128 + rb2) * E + lane;
#pragma unroll
      for (int rq = 0; rq < 4; ++rq) {
        short4v h;
#pragma unroll
        for (int j = 0; j < 4; ++j) {
          h[j] = f2bf(vp[(size_t)(rq * 4 + j) * E]);
        }
        *(short4v*)(Vt + lane * VT_LD + rb2 + rq * 4) = h;
      }
      // P chunk (C-layout regs) -> per-wave LDS buffer, row-major
      short* pw = Pb + wid * PB_STRIDE;
#pragma unroll
      for (int cc = 0; cc < 8; ++cc) {
        const int ct = c * 8 + cc;
#pragma unroll
        for (int r = 0; r < 4; ++r) {
          pw[(lg * 4 + r) * VT_LD + cc * 16 + li] = f2bf(S[ct][r]);
        }
      }
    }
    __syncthreads();
    if (active) {
      short8 aP[4];
      const short* pr = Pb + wid * PB_STRIDE + li * VT_LD + lg * 8;
#pragma unroll
      for (int kt = 0; kt < 4; ++kt) aP[kt] = *(const short8*)(pr + kt * 32);
#pragma unroll
      for (int kt = 0; kt < 4; ++kt) {
#pragma unroll
        for (int nt = 0; nt < 4; ++nt) {
          short8 b = *(const short8*)(Vt + (nt * 16 + li) * VT_LD + kt * 32 + lg * 8);
          O[nt] = __builtin_amdgcn_mfma_f32_16x16x32_bf16(aP[kt], b, O[nt], 0, 0, 0);
        }
      }
    }
    __syncthreads();   // chunk 1 restage must not race chunk 0 PV reads
  }

  // ---- epilogue: apply 1/l, store fp32 ----
  float* op = outg + base + (size_t)(w * 128 + rowb) * E;
#pragma unroll
  for (int r = 0; r < 4; ++r) {
#pragma unroll
    for (int nt = 0; nt < 4; ++nt) {
      op[(size_t)r * E + nt * 16 + li] = O[nt][r] * linv[r];
    }
  }
}

extern "C" void kernel_launch(void* const* d_in, const int* in_sizes, int n_in,
                              void* d_out, int out_size, void* d_ws, size_t ws_size,
                              hipStream_t stream) {
  const float* q  = (const float*)d_in[0];
  const float* k  = (const float*)d_in[1];
  const float* qr = (const float*)d_in[2];
  const float* kr = (const float*)d_in[3];
  const float* v  = (const float*)d_in[4];
  float* out = (float*)d_out;
  dim3 grid(NWIN, NBH);
  la_kernel<<<grid, dim3(512), SMEM_BYTES, stream>>>(q, k, qr, kr, v, out);
}

// Round 3
// 220.136 us; speedup vs baseline: 1.1474x; 1.1474x over previous
//
#include <hip/hip_runtime.h>
#include <stdint.h>

#define T 4096
#define E 64
#define NWIN 32
#define NBH 32
#define KK_LD 136              // 128 + 8 pad (bf16 elems) — KK chunk rows
#define VT_LD 136              // 128 + 8 pad — Vt rows (keypos-major)
#define PB_LD 144              // 128 + 16 pad — 72 dwords ≡ 8 (mod 32): row groups on disjoint banks
#define PB_STRIDE (16*PB_LD)
#define VT_BYTES (64*VT_LD*2)                 // 17408
#define SMEM_BYTES (VT_BYTES + 8*PB_STRIDE*2) // 17408 + 36864 = 54272 (KK chunk 34816 fits under)

typedef __attribute__((ext_vector_type(8))) short short8;
typedef __attribute__((ext_vector_type(4))) short short4v;
typedef __attribute__((ext_vector_type(4))) float f32x4;

__device__ __forceinline__ short f2bf(float x) {
  unsigned u = __float_as_uint(x);
  u += 0x7fffu + ((u >> 16) & 1u);   // round-to-nearest-even
  return (short)(u >> 16);
}

// One block per (window, bh). 8 waves, each owns 16 q-rows.
// Flash two-chunk: keys processed 128 at a time; single 54.3 KB LDS region
// time-shared between KK-chunk [128][136] and (Vt [64][136] + Pb [8][16][144]).
// S chunk = 32 VGPRs -> fits 128-VGPR cap -> 2 blocks/CU.
__global__ __launch_bounds__(512, 4)
void la_kernel(const float* __restrict__ qg, const float* __restrict__ kg,
               const float* __restrict__ qrg, const float* __restrict__ krg,
               const float* __restrict__ vg, float* __restrict__ outg) {
  extern __shared__ char smem[];
  short* KK = (short*)smem;                 // S-phase: [128][136] = [K|Kr] bf16
  short* Vt = (short*)smem;                 // PV-phase: [64][136]
  short* Pb = (short*)(smem + VT_BYTES);    // PV-phase: [8][16][144]

  const int w   = blockIdx.x;
  const int bh  = blockIdx.y;
  const int tid = threadIdx.x;
  const int wid  = tid >> 6;    // wave 0..7
  const int lane = tid & 63;
  const int li = lane & 15;
  const int lg = lane >> 4;

  const size_t base = (size_t)bh * T * E;
  const int krow0 = w * 128 - 128;   // global t-row of key chunk 0, row 0
  const int rowb = wid * 16 + lg * 4;

  // ---- Q/Qr -> A-fragments in registers (scale 0.125 folded; exact pow2) ----
  // A-layout: lane holds A[m=li][k = kt*32 + lg*8 + j], k-dim = [Q e0..63 | Qr e0..63]
  const int qrow = w * 128 + wid * 16 + li;
  const float* qp  = qg  + base + (size_t)qrow * E;
  const float* qrp = qrg + base + (size_t)qrow * E;
  short8 aF[4];
#pragma unroll
  for (int kt = 0; kt < 4; ++kt) {
    const float* sp = (kt < 2 ? qp : qrp) + (kt & 1) * 32 + lg * 8;
    float4 f0 = *(const float4*)sp;
    float4 f1 = *(const float4*)(sp + 4);
    short8 a;
    a[0]=f2bf(f0.x*0.125f); a[1]=f2bf(f0.y*0.125f); a[2]=f2bf(f0.z*0.125f); a[3]=f2bf(f0.w*0.125f);
    a[4]=f2bf(f1.x*0.125f); a[5]=f2bf(f1.y*0.125f); a[6]=f2bf(f1.z*0.125f); a[7]=f2bf(f1.w*0.125f);
    aF[kt] = a;
  }

  f32x4 O[4] = {{0,0,0,0},{0,0,0,0},{0,0,0,0},{0,0,0,0}};
  float m_run[4] = {-1e30f, -1e30f, -1e30f, -1e30f};
  float l_run[4] = {0.f, 0.f, 0.f, 0.f};

#pragma unroll 1
  for (int c = 0; c < 2; ++c) {
    if (w == 0 && c == 0) continue;   // chunk 0 of window 0 is all padding (block-uniform)
    const int kbase = krow0 + c * 128;   // >= 0 whenever active

    // ---- stage KK chunk: [128 keys][K e0..63 | Kr e0..63] ----
#pragma unroll
    for (int m = 0; m < 2; ++m) {
      const float* src = m ? krg : kg;
#pragma unroll
      for (int it = 0; it < 4; ++it) {
        int idx = it * 512 + tid;
        int row = idx >> 4, c4 = idx & 15;
        float4 f = *(const float4*)(src + base + (size_t)(kbase + row) * E + c4 * 4);
        short4v h = { f2bf(f.x), f2bf(f.y), f2bf(f.z), f2bf(f.w) };
        *(short4v*)(KK + row * KK_LD + m * 64 + c4 * 4) = h;
      }
    }
    __syncthreads();

    // ---- S chunk = [Q|Qr]·[K|Kr]^T : 8 col-tiles x 4 k-tiles ----
    // C-layout: lane holds S[row = lg*4 + r][col = ct*16 + li]
    f32x4 S[8];
#pragma unroll
    for (int ct = 0; ct < 8; ++ct) {
      f32x4 acc = {0.f, 0.f, 0.f, 0.f};
      const short* kb = KK + (ct * 16 + li) * KK_LD + lg * 8;
#pragma unroll
      for (int kt = 0; kt < 4; ++kt) {
        short8 b = *(const short8*)(kb + kt * 32);
        acc = __builtin_amdgcn_mfma_f32_16x16x32_bf16(aF[kt], b, acc, 0, 0, 0);
      }
      S[ct] = acc;
    }

    // ---- mask (chunk 1: causal within window) + online softmax update ----
    float alpha[4];
#pragma unroll
    for (int r = 0; r < 4; ++r) {
      const int qi = rowb + r;   // 0..127 within window
      float mx = -1e30f;
#pragma unroll
      for (int ct = 0; ct < 8; ++ct) {
        if (c == 1) {
          int jj = ct * 16 + li;
          if (jj > qi) S[ct][r] = -1e30f;
        }
        mx = fmaxf(mx, S[ct][r]);
      }
      mx = fmaxf(mx, __shfl_xor(mx, 1));
      mx = fmaxf(mx, __shfl_xor(mx, 2));
      mx = fmaxf(mx, __shfl_xor(mx, 4));
      mx = fmaxf(mx, __shfl_xor(mx, 8));
      float m_new = fmaxf(m_run[r], mx);
      float al = __expf(m_run[r] - m_new);
      float sm = 0.f;
#pragma unroll
      for (int ct = 0; ct < 8; ++ct) {
        float e = __expf(S[ct][r] - m_new);
        S[ct][r] = e;
        sm += e;
      }
      sm += __shfl_xor(sm, 1);
      sm += __shfl_xor(sm, 2);
      sm += __shfl_xor(sm, 4);
      sm += __shfl_xor(sm, 8);
      l_run[r] = l_run[r] * al + sm;
      m_run[r] = m_new;
      alpha[r] = al;
    }
#pragma unroll
    for (int nt = 0; nt < 4; ++nt)
#pragma unroll
      for (int r = 0; r < 4; ++r)
        O[nt][r] *= alpha[r];

    __syncthreads();   // all waves done reading KK chunk before Pb/Vt overlay it

    // ---- P chunk -> per-wave LDS (bf16), V chunk -> Vt transposed ----
    short* pw = Pb + wid * PB_STRIDE;
#pragma unroll
    for (int ct = 0; ct < 8; ++ct) {
#pragma unroll
      for (int r = 0; r < 4; ++r) {
        pw[(lg * 4 + r) * PB_LD + ct * 16 + li] = f2bf(S[ct][r]);
      }
    }
    {
      // Vt[e][keypos]: e = lane (64 distinct e/wave), wave wid covers keypos wid*16..+15
      const float* vp = vg + base + (size_t)(kbase + wid * 16) * E + lane;
#pragma unroll
      for (int rq = 0; rq < 4; ++rq) {
        short4v h;
#pragma unroll
        for (int j = 0; j < 4; ++j) {
          h[j] = f2bf(vp[(size_t)(rq * 4 + j) * E]);
        }
        *(short4v*)(Vt + lane * VT_LD + wid * 16 + rq * 4) = h;
      }
    }
    __syncthreads();

    // ---- O += P·V : 4 k-tiles x 4 n-tiles ----
    short8 aP[4];
    const short* pr = Pb + wid * PB_STRIDE + li * PB_LD + lg * 8;
#pragma unroll
    for (int kt = 0; kt < 4; ++kt) aP[kt] = *(const short8*)(pr + kt * 32);
#pragma unroll
    for (int kt = 0; kt < 4; ++kt) {
#pragma unroll
      for (int nt = 0; nt < 4; ++nt) {
        short8 b = *(const short8*)(Vt + (nt * 16 + li) * VT_LD + kt * 32 + lg * 8);
        O[nt] = __builtin_amdgcn_mfma_f32_16x16x32_bf16(aP[kt], b, O[nt], 0, 0, 0);
      }
    }
    __syncthreads();   // protect next chunk's KK stage from racing these reads
  }

  // ---- epilogue: apply 1/l, store fp32 ----
  float* op = outg + base + (size_t)(w * 128 + rowb) * E;
#pragma unroll
  for (int r = 0; r < 4; ++r) {
    float linv = 1.f / l_run[r];
#pragma unroll
    for (int nt = 0; nt < 4; ++nt) {
      op[(size_t)r * E + nt * 16 + li] = O[nt][r] * linv;
    }
  }
}

extern "C" void kernel_launch(void* const* d_in, const int* in_sizes, int n_in,
                              void* d_out, int out_size, void* d_ws, size_t ws_size,
                              hipStream_t stream) {
  const float* q  = (const float*)d_in[0];
  const float* k  = (const float*)d_in[1];
  const float* qr = (const float*)d_in[2];
  const float* kr = (const float*)d_in[3];
  const float* v  = (const float*)d_in[4];
  float* out = (float*)d_out;
  dim3 grid(NWIN, NBH);
  la_kernel<<<grid, dim3(512), SMEM_BYTES, stream>>>(q, k, qr, kr, v, out);
}